// Round 1
// baseline (915.452 us; speedup 1.0000x reference)
//
#include <hip/hip_runtime.h>
#include <math.h>

typedef __attribute__((ext_vector_type(4))) float f32x4;

// Problem constants (DeepSeek-V3 gate: hidden (4,2048,7168), 256 experts)
constexpr int H       = 7168;
constexpr int E       = 256;
constexpr int T_TOTAL = 8192;      // 4*2048 tokens
constexpr int TPB     = 32;        // tokens per block
constexpr int HC      = 32;        // H-chunk staged in LDS
constexpr int WS      = 260;       // w_lds row stride (words): 256 + 4 pad, keeps 16B align, breaks bank aliasing
constexpr int SCS     = 260;       // scores row stride per token (same reasons)
constexpr int NTHR    = 512;       // 8 waves

constexpr int N_GROUP    = 8;
constexpr int GROUP_SZ   = E / N_GROUP;   // 32
constexpr int TOPK_GROUP = 4;
constexpr int TOP_K      = 8;

__global__ __launch_bounds__(NTHR) void moe_gate_kernel(
    const float* __restrict__ x,      // [T_TOTAL, H]
    const float* __restrict__ w,      // [E, H]
    const float* __restrict__ bias,   // [E]
    float* __restrict__ out)          // [T*8 idx floats][T*8 weight floats]
{
    // LDS: w-tile (h-major) reused as scores after the GEMM; x-tile; bias.
    __shared__ float smem[HC * WS + TPB * HC + E];
    float* w_lds    = smem;                 // [HC][WS]
    float* sc_lds   = smem;                 // [TPB][SCS]  (union with w_lds)
    float* x_lds    = smem + HC * WS;       // [TPB][HC]
    float* bias_lds = x_lds + TPB * HC;     // [E]

    const int tid = threadIdx.x;
    const int te  = tid & 63;     // expert-quad id: owns experts 4*te..4*te+3
    const int wid = tid >> 6;     // wave id: owns tokens 4*wid..4*wid+3 (block-local)
    const int t0  = blockIdx.x * TPB;

    if (tid < E) bias_lds[tid] = bias[tid];

    float acc[4][4];              // [expert j][token t]
    #pragma unroll
    for (int j = 0; j < 4; ++j)
        #pragma unroll
        for (int t = 0; t < 4; ++t) acc[j][t] = 0.f;

    for (int h0 = 0; h0 < H; h0 += HC) {
        // ---- prefetch globals into registers (before barrier) ----
        f32x4 wg[4];
        #pragma unroll
        for (int i = 0; i < 4; ++i) {
            const int L  = tid + NTHR * i;          // 0..2047
            const int e  = L >> 3;                  // 0..255
            const int hq = L & 7;                   // 0..7 (16B quad within chunk row)
            wg[i] = *reinterpret_cast<const f32x4*>(&w[(size_t)e * H + h0 + 4 * hq]);
        }
        f32x4 xg;
        if (tid < TPB * 8) {                        // 256 loader threads
            const int t  = tid >> 3;
            const int hq = tid & 7;
            xg = *reinterpret_cast<const f32x4*>(&x[(size_t)(t0 + t) * H + h0 + 4 * hq]);
        }
        __syncthreads();   // previous chunk's compute reads are done
        // ---- LDS stores ----
        #pragma unroll
        for (int i = 0; i < 4; ++i) {
            const int L  = tid + NTHR * i;
            const int e  = L >> 3;
            const int hq = L & 7;
            #pragma unroll
            for (int k = 0; k < 4; ++k)
                w_lds[(4 * hq + k) * WS + e] = wg[i][k];   // transpose to h-major
        }
        if (tid < TPB * 8) {
            const int t  = tid >> 3;
            const int hq = tid & 7;
            *reinterpret_cast<f32x4*>(&x_lds[t * HC + 4 * hq]) = xg;
        }
        __syncthreads();
        // ---- compute: 4 experts x 4 tokens per thread ----
        #pragma unroll
        for (int h = 0; h < HC; h += 4) {
            f32x4 xv[4], wv[4];
            #pragma unroll
            for (int t = 0; t < 4; ++t)   // wave-uniform address -> LDS broadcast
                xv[t] = *reinterpret_cast<const f32x4*>(&x_lds[(4 * wid + t) * HC + h]);
            #pragma unroll
            for (int k = 0; k < 4; ++k)   // lane-consecutive 16B -> conflict-free
                wv[k] = *reinterpret_cast<const f32x4*>(&w_lds[(h + k) * WS + 4 * te]);
            #pragma unroll
            for (int k = 0; k < 4; ++k)
                #pragma unroll
                for (int t = 0; t < 4; ++t)
                    #pragma unroll
                    for (int j = 0; j < 4; ++j)
                        acc[j][t] = fmaf(wv[k][j], xv[t][k], acc[j][t]);
        }
    }

    __syncthreads();   // GEMM reads of w_lds done; safe to overwrite with scores
    // ---- unbiased sigmoid scores -> sc_lds[t][e] ----
    #pragma unroll
    for (int t = 0; t < 4; ++t) {
        f32x4 sv;
        #pragma unroll
        for (int j = 0; j < 4; ++j)
            sv[j] = 1.0f / (1.0f + expf(-acc[j][t]));
        *reinterpret_cast<f32x4*>(&sc_lds[(4 * wid + t) * SCS + 4 * te]) = sv;
    }
    __syncthreads();

    // ---- gating: one thread per token (serial; tiny vs GEMM) ----
    if (tid < TPB) {
        const float* sc = &sc_lds[tid * SCS];
        // group scores = sum of top-2 biased scores in each group of 32
        float gs[N_GROUP];
        #pragma unroll
        for (int g = 0; g < N_GROUP; ++g) {
            const int base = g * GROUP_SZ;
            float m1 = -INFINITY, m2 = -INFINITY;
            for (int i = 0; i < GROUP_SZ; ++i) {
                const float v = sc[base + i] + bias_lds[base + i];
                if (v > m1) { m2 = m1; m1 = v; }
                else if (v > m2) { m2 = v; }
            }
            gs[g] = m1 + m2;
        }
        // top-4 groups (ties -> lowest index, matches lax.top_k)
        bool gsel[N_GROUP] = {false, false, false, false, false, false, false, false};
        for (int r = 0; r < TOPK_GROUP; ++r) {
            float best = -INFINITY; int bi = 0;
            for (int g = 0; g < N_GROUP; ++g)
                if (!gsel[g] && gs[g] > best) { best = gs[g]; bi = g; }
            gsel[bi] = true;
        }
        int ag[TOPK_GROUP]; int na = 0;
        for (int g = 0; g < N_GROUP; ++g) if (gsel[g]) ag[na++] = g;  // ascending
        // top-8 experts among allowed groups (descending, ties -> lowest index)
        unsigned long long selmask[4] = {0ull, 0ull, 0ull, 0ull};
        int   idx[TOP_K];
        float wts[TOP_K];
        float wsum = 0.f;
        for (int r = 0; r < TOP_K; ++r) {
            float best = -INFINITY; int bi = -1;
            for (int a = 0; a < TOPK_GROUP; ++a) {
                const int base = ag[a] * GROUP_SZ;
                for (int i = 0; i < GROUP_SZ; ++i) {
                    const int e = base + i;
                    if ((selmask[e >> 6] >> (e & 63)) & 1ull) continue;
                    const float v = sc[e] + bias_lds[e];
                    if (v > best) { best = v; bi = e; }
                }
            }
            selmask[bi >> 6] |= 1ull << (bi & 63);
            idx[r] = bi;
            const float s = sc[bi];     // UNBIASED score for the weight
            wts[r] = s;
            wsum  += s;
        }
        const float scale = 2.5f / wsum;
        const int t_glob = t0 + tid;
        float* out_idx = out;
        float* out_wt  = out + (size_t)T_TOTAL * TOP_K;
        #pragma unroll
        for (int r = 0; r < TOP_K; ++r) {
            out_idx[t_glob * TOP_K + r] = (float)idx[r];
            out_wt [t_glob * TOP_K + r] = wts[r] * scale;
        }
    }
}

extern "C" void kernel_launch(void* const* d_in, const int* in_sizes, int n_in,
                              void* d_out, int out_size, void* d_ws, size_t ws_size,
                              hipStream_t stream) {
    const float* x    = (const float*)d_in[0];   // hidden_states [4,2048,7168]
    const float* w    = (const float*)d_in[1];   // weight [256,7168]
    const float* bias = (const float*)d_in[2];   // e_score_correction_bias [256]
    float* out = (float*)d_out;                  // [65536 idx][65536 weights]
    dim3 grid(T_TOTAL / TPB), block(NTHR);
    hipLaunchKernelGGL(moe_gate_kernel, grid, block, 0, stream, x, w, bias, out);
}

// Round 2
// 596.730 us; speedup vs baseline: 1.5341x; 1.5341x over previous
//
#include <hip/hip_runtime.h>
#include <math.h>

typedef __attribute__((ext_vector_type(4))) float f32x4;
typedef _Float16 f16;
typedef __attribute__((ext_vector_type(8))) _Float16 f16x8;

// Problem constants (DeepSeek-V3 gate: hidden (4,2048,7168), 256 experts)
constexpr int H       = 7168;
constexpr int E       = 256;
constexpr int T_TOTAL = 8192;   // 4*2048 tokens

constexpr int N_GROUP    = 8;
constexpr int GROUP_SZ   = E / N_GROUP;   // 32
constexpr int TOPK_GROUP = 4;
constexpr int TOP_K      = 8;

constexpr int SCS = 261;        // score row stride (words); 261 coprime 32 -> conflict-free column scans
constexpr int XS  = 136;        // x_lds token-row stride in f16: 64 hi + 64 lo + 8 pad (keeps b128 even across banks)

// ---------------------------------------------------------------------------
// Kernel 1: split w (fp32) into f16 hi/lo, laid out in MFMA B-fragment order:
//   wf[f16 idx] = ((kc*16 + ntile)*2 + s)*512 + lane*8 + j
// where kc = h>>5 (K-chunk of 32), ntile = e>>4, s = 0(hi)/1(lo),
//       lane = ((h>>3)&3)<<4 | (e&15)   (MFMA 16x16x32: n=lane&15, k=(lane>>4)*8+j)
// GEMM then loads each wave's B-fragment as one coalesced dwordx4 per lane.
// ---------------------------------------------------------------------------
__global__ __launch_bounds__(64) void pack_w_kernel(const float* __restrict__ w,
                                                    f16* __restrict__ wf)
{
    const int l  = threadIdx.x;        // lane 0..63
    const int nt = blockIdx.x & 15;    // ntile 0..15
    const int kc = blockIdx.x >> 4;    // kchunk 0..223
    const int e  = nt * 16 + (l & 15);
    const int h  = kc * 32 + (l >> 4) * 8;
    const float* src = &w[(size_t)e * H + h];
    f32x4 v0 = *reinterpret_cast<const f32x4*>(src);
    f32x4 v1 = *reinterpret_cast<const f32x4*>(src + 4);
    float v[8] = {v0[0], v0[1], v0[2], v0[3], v1[0], v1[1], v1[2], v1[3]};
    f16x8 hi, lo;
    #pragma unroll
    for (int j = 0; j < 8; ++j) {
        f16 h16 = (f16)v[j];
        hi[j] = h16;
        lo[j] = (f16)(v[j] - (float)h16);
    }
    const size_t base = (((size_t)kc * 16 + nt) * 2) * 512 + (size_t)l * 8;
    *reinterpret_cast<f16x8*>(&wf[base])       = hi;
    *reinterpret_cast<f16x8*>(&wf[base + 512]) = lo;   // s=1 slot
}

// ---------------------------------------------------------------------------
// Kernel 2: fused router GEMM (f16 split-MFMA) + sigmoid + grouped top-k gating
// Grid: 256 blocks x 256 threads (4 waves). Block = 32 tokens x all 256 experts.
// Wave tile: 32m x 64n = 2 mtiles x 4 ntiles of 16x16; acc = 2x4 f32x4.
// Split GEMM: acc += Ahi*Bhi + Ahi*Blo + Alo*Bhi  (lo*lo dropped, ~1e-6 logits)
// ---------------------------------------------------------------------------
__global__ __launch_bounds__(256, 3) void moe_gate_mfma(
    const float* __restrict__ x,      // [T_TOTAL, H] fp32
    const f16*   __restrict__ wf,     // packed B-fragments (kernel 1)
    const float* __restrict__ bias,   // [E]
    float* __restrict__ out)          // [T*8 idx floats][T*8 weight floats]
{
    // x_lds (8704 B, GEMM phase) unions with sc_lds (33408 B, gating phase)
    __shared__ __align__(16) char smem_raw[32 * SCS * 4 + E * 4];
    f16*   x_lds    = reinterpret_cast<f16*>(smem_raw);
    float* sc_lds   = reinterpret_cast<float*>(smem_raw);
    float* bias_lds = reinterpret_cast<float*>(smem_raw + 32 * SCS * 4);

    const int tid  = threadIdx.x;
    const int lane = tid & 63;
    const int wave = tid >> 6;       // 0..3, owns experts wave*64 .. +63
    const int lm   = lane & 15;      // MFMA row (A) / col (B/C)
    const int kq   = lane >> 4;      // MFMA k-quad
    const int t0   = blockIdx.x * 32;

    if (tid < E) bias_lds[tid] = bias[tid];

    f32x4 acc[2][4];
    #pragma unroll
    for (int mt = 0; mt < 2; ++mt)
        #pragma unroll
        for (int nt = 0; nt < 4; ++nt)
            acc[mt][nt] = (f32x4){0.f, 0.f, 0.f, 0.f};

    // x loader mapping: 256 threads cover 32 rows x 8 segments of 8 floats (BK=64)
    const int row = tid >> 3;
    const int seg = tid & 7;
    const float* xrow = &x[(size_t)(t0 + row) * H + seg * 8];

    for (int ch = 0; ch < H / 64; ++ch) {              // 112 chunks of BK=64
        // global fp32 x for this chunk (issued before the barrier -> overlaps)
        f32x4 v0 = *reinterpret_cast<const f32x4*>(xrow + ch * 64);
        f32x4 v1 = *reinterpret_cast<const f32x4*>(xrow + ch * 64 + 4);
        __syncthreads();                               // prior chunk's A reads done
        {
            float v[8] = {v0[0], v0[1], v0[2], v0[3], v1[0], v1[1], v1[2], v1[3]};
            f16x8 hi, lo;
            #pragma unroll
            for (int j = 0; j < 8; ++j) {
                f16 h16 = (f16)v[j];
                hi[j] = h16;
                lo[j] = (f16)(v[j] - (float)h16);
            }
            *reinterpret_cast<f16x8*>(&x_lds[row * XS + seg * 8])      = hi;
            *reinterpret_cast<f16x8*>(&x_lds[row * XS + 64 + seg * 8]) = lo;
        }
        __syncthreads();

        #pragma unroll
        for (int ks = 0; ks < 2; ++ks) {               // two K=32 steps per chunk
            const int kc = ch * 2 + ks;
            // B fragments straight from global (L2-resident packed wf)
            f16x8 b[4][2];
            #pragma unroll
            for (int nt = 0; nt < 4; ++nt)
                #pragma unroll
                for (int s = 0; s < 2; ++s)
                    b[nt][s] = *reinterpret_cast<const f16x8*>(
                        &wf[(((size_t)kc * 16 + wave * 4 + nt) * 2 + s) * 512 + lane * 8]);
            // A fragments from LDS (conflict-free b128)
            f16x8 a[2][2];
            #pragma unroll
            for (int mt = 0; mt < 2; ++mt)
                #pragma unroll
                for (int s = 0; s < 2; ++s)
                    a[mt][s] = *reinterpret_cast<const f16x8*>(
                        &x_lds[(mt * 16 + lm) * XS + s * 64 + ks * 32 + kq * 8]);
            // hi*hi
            #pragma unroll
            for (int mt = 0; mt < 2; ++mt)
                #pragma unroll
                for (int nt = 0; nt < 4; ++nt)
                    acc[mt][nt] = __builtin_amdgcn_mfma_f32_16x16x32_f16(
                        a[mt][0], b[nt][0], acc[mt][nt], 0, 0, 0);
            // hi*lo
            #pragma unroll
            for (int mt = 0; mt < 2; ++mt)
                #pragma unroll
                for (int nt = 0; nt < 4; ++nt)
                    acc[mt][nt] = __builtin_amdgcn_mfma_f32_16x16x32_f16(
                        a[mt][0], b[nt][1], acc[mt][nt], 0, 0, 0);
            // lo*hi
            #pragma unroll
            for (int mt = 0; mt < 2; ++mt)
                #pragma unroll
                for (int nt = 0; nt < 4; ++nt)
                    acc[mt][nt] = __builtin_amdgcn_mfma_f32_16x16x32_f16(
                        a[mt][1], b[nt][0], acc[mt][nt], 0, 0, 0);
        }
    }

    __syncthreads();   // x_lds reads done; safe to overwrite with scores
    // unbiased sigmoid scores -> sc_lds[token][expert]
    // C/D layout: col(expert-in-tile)=lane&15, row(token-in-tile)=(lane>>4)*4+reg
    #pragma unroll
    for (int mt = 0; mt < 2; ++mt)
        #pragma unroll
        for (int nt = 0; nt < 4; ++nt)
            #pragma unroll
            for (int r = 0; r < 4; ++r) {
                const int token  = mt * 16 + kq * 4 + r;
                const int expert = wave * 64 + nt * 16 + lm;
                sc_lds[token * SCS + expert] = 1.0f / (1.0f + expf(-acc[mt][nt][r]));
            }
    __syncthreads();

    // ---- gating: one thread per token (SIMD across 32 tokens) ----
    if (tid < 32) {
        const float* sc = &sc_lds[tid * SCS];
        float gs[N_GROUP];
        #pragma unroll
        for (int g = 0; g < N_GROUP; ++g) {
            const int base = g * GROUP_SZ;
            float m1 = -INFINITY, m2 = -INFINITY;
            for (int i = 0; i < GROUP_SZ; ++i) {
                const float v = sc[base + i] + bias_lds[base + i];
                if (v > m1) { m2 = m1; m1 = v; }
                else if (v > m2) { m2 = v; }
            }
            gs[g] = m1 + m2;
        }
        bool gsel[N_GROUP] = {false, false, false, false, false, false, false, false};
        for (int r = 0; r < TOPK_GROUP; ++r) {
            float best = -INFINITY; int bi = 0;
            for (int g = 0; g < N_GROUP; ++g)
                if (!gsel[g] && gs[g] > best) { best = gs[g]; bi = g; }
            gsel[bi] = true;
        }
        int ag[TOPK_GROUP]; int na = 0;
        for (int g = 0; g < N_GROUP; ++g) if (gsel[g]) ag[na++] = g;
        unsigned long long selmask[4] = {0ull, 0ull, 0ull, 0ull};
        int   idx[TOP_K];
        float wts[TOP_K];
        float wsum = 0.f;
        for (int r = 0; r < TOP_K; ++r) {
            float best = -INFINITY; int bi = -1;
            for (int a = 0; a < TOPK_GROUP; ++a) {
                const int base = ag[a] * GROUP_SZ;
                for (int i = 0; i < GROUP_SZ; ++i) {
                    const int e = base + i;
                    if ((selmask[e >> 6] >> (e & 63)) & 1ull) continue;
                    const float v = sc[e] + bias_lds[e];
                    if (v > best) { best = v; bi = e; }
                }
            }
            selmask[bi >> 6] |= 1ull << (bi & 63);
            idx[r] = bi;
            const float s = sc[bi];   // UNBIASED score for the weight
            wts[r] = s;
            wsum  += s;
        }
        const float scale = 2.5f / wsum;
        const int t_glob = t0 + tid;
        float* out_idx = out;
        float* out_wt  = out + (size_t)T_TOTAL * TOP_K;
        #pragma unroll
        for (int r = 0; r < TOP_K; ++r) {
            out_idx[t_glob * TOP_K + r] = (float)idx[r];
            out_wt [t_glob * TOP_K + r] = wts[r] * scale;
        }
    }
}

extern "C" void kernel_launch(void* const* d_in, const int* in_sizes, int n_in,
                              void* d_out, int out_size, void* d_ws, size_t ws_size,
                              hipStream_t stream) {
    const float* x    = (const float*)d_in[0];   // hidden_states [4,2048,7168]
    const float* w    = (const float*)d_in[1];   // weight [256,7168]
    const float* bias = (const float*)d_in[2];   // e_score_correction_bias [256]
    float* out = (float*)d_out;
    f16*   wf  = (f16*)d_ws;                     // 7.34 MB packed split-w fragments

    hipLaunchKernelGGL(pack_w_kernel, dim3((H / 32) * 16), dim3(64), 0, stream, w, wf);
    hipLaunchKernelGGL(moe_gate_mfma, dim3(T_TOTAL / 32), dim3(256), 0, stream,
                       x, wf, bias, out);
}

// Round 3
// 471.120 us; speedup vs baseline: 1.9431x; 1.2666x over previous
//
#include <hip/hip_runtime.h>
#include <math.h>

typedef __attribute__((ext_vector_type(4))) float f32x4;
typedef _Float16 f16;
typedef __attribute__((ext_vector_type(8))) _Float16 f16x8;

// Problem constants (DeepSeek-V3 gate: hidden (4,2048,7168), 256 experts)
constexpr int H       = 7168;
constexpr int E       = 256;
constexpr int T_TOTAL = 8192;     // 4*2048 tokens

constexpr int KSPLIT  = 4;
constexpr int K_SLICE = H / KSPLIT;    // 1792
constexpr int BK      = 64;            // K-chunk per LDS stage
constexpr int NCH     = K_SLICE / BK;  // 28 chunks per block
constexpr int MT      = 64;            // tokens per GEMM block
constexpr int XS      = 136;           // x_lds row stride in f16: 64 hi + 64 lo + 8 pad

constexpr int N_GROUP    = 8;
constexpr int GROUP_SZ   = E / N_GROUP;   // 32
constexpr int TOPK_GROUP = 4;
constexpr int TOP_K      = 8;
constexpr int SCS        = 261;           // score row stride (coprime 32)

// ws layout: [0, 7.34MB) packed wf fragments; [8MB, 8MB+33.6MB) partial logits
constexpr size_t WF_BYTES     = (size_t)E * H * 2 * sizeof(f16);  // 7,340,032
constexpr size_t SCORES_OFF   = 8u * 1024 * 1024;                 // aligned past wf

// ---------------------------------------------------------------------------
// Kernel 1: split w (fp32) into f16 hi/lo in MFMA B-fragment order:
//   wf[((kc*16 + ntile)*2 + s)*512 + lane*8 + j]
//   kc = h>>5, ntile = e>>4, s = 0(hi)/1(lo), lane = ((h>>3)&3)<<4 | (e&15)
// ---------------------------------------------------------------------------
__global__ __launch_bounds__(64) void pack_w_kernel(const float* __restrict__ w,
                                                    f16* __restrict__ wf)
{
    const int l  = threadIdx.x;
    const int nt = blockIdx.x & 15;
    const int kc = blockIdx.x >> 4;
    const int e  = nt * 16 + (l & 15);
    const int h  = kc * 32 + (l >> 4) * 8;
    const float* src = &w[(size_t)e * H + h];
    f32x4 v0 = *reinterpret_cast<const f32x4*>(src);
    f32x4 v1 = *reinterpret_cast<const f32x4*>(src + 4);
    float v[8] = {v0[0], v0[1], v0[2], v0[3], v1[0], v1[1], v1[2], v1[3]};
    f16x8 hi, lo;
    #pragma unroll
    for (int j = 0; j < 8; ++j) {
        f16 h16 = (f16)v[j];
        hi[j] = h16;
        lo[j] = (f16)(v[j] - (float)h16);
    }
    const size_t base = (((size_t)kc * 16 + nt) * 2) * 512 + (size_t)l * 8;
    *reinterpret_cast<f16x8*>(&wf[base])       = hi;
    *reinterpret_cast<f16x8*>(&wf[base + 512]) = lo;
}

// ---------------------------------------------------------------------------
// Kernel 2: router GEMM, f16-split MFMA, K-split partials.
// Grid: 512 = 128 M-tiles x 4 K-slices; kslice = bid&3 so each XCD (bid%8)
// sees ONE K-slice of wf (1.84 MB -> L2-resident). Block: 512 thr = 8 waves,
// tile 64m x 256n; wave tile 32m x 64n (2 mtiles x 4 ntiles).
// acc += Ahi*Bhi + Ahi*Blo + Alo*Bhi (lo*lo dropped; ~1e-6 on logits).
// ---------------------------------------------------------------------------
__global__ __launch_bounds__(512, 4) void gemm_kernel(
    const float* __restrict__ x,      // [T_TOTAL, H] fp32
    const f16*   __restrict__ wf,     // packed B-fragments
    float* __restrict__ scores)       // [KSPLIT][T_TOTAL][E] partial logits
{
    __shared__ __align__(16) f16 x_lds[2][MT * XS];   // 34,816 B

    const int tid  = threadIdx.x;
    const int lane = tid & 63;
    const int wave = tid >> 6;     // 0..7
    const int wm   = wave >> 2;    // 0..1  (m offset 32 rows)
    const int wn   = wave & 3;     // 0..3  (experts wn*64..+63)
    const int lm   = lane & 15;
    const int kq   = lane >> 4;

    const int bid = blockIdx.x;
    const int ksl = bid & 3;       // K-slice (constant per XCD under bid%8 swizzle)
    const int mb  = bid >> 2;      // M-tile 0..127
    const int t0  = mb * MT;
    const int k0  = ksl * K_SLICE;

    // x loader: 512 threads = 64 rows x 8 segments of 8 floats (BK=64)
    const int row = tid >> 3;
    const int seg = tid & 7;
    const float* xrow = &x[(size_t)(t0 + row) * H + k0 + seg * 8];

    f32x4 acc[2][4];
    #pragma unroll
    for (int mt = 0; mt < 2; ++mt)
        #pragma unroll
        for (int nt = 0; nt < 4; ++nt)
            acc[mt][nt] = (f32x4){0.f, 0.f, 0.f, 0.f};

    // split fp32 -> f16 hi/lo and stage into LDS buffer
    auto stage = [&](int buf, f32x4 v0, f32x4 v1) {
        float v[8] = {v0[0], v0[1], v0[2], v0[3], v1[0], v1[1], v1[2], v1[3]};
        f16x8 hi, lo;
        #pragma unroll
        for (int j = 0; j < 8; ++j) {
            f16 h16 = (f16)v[j];
            hi[j] = h16;
            lo[j] = (f16)(v[j] - (float)h16);
        }
        *reinterpret_cast<f16x8*>(&x_lds[buf][row * XS + seg * 8])      = hi;
        *reinterpret_cast<f16x8*>(&x_lds[buf][row * XS + 64 + seg * 8]) = lo;
    };

    // prologue: stage chunk 0
    {
        f32x4 v0 = *reinterpret_cast<const f32x4*>(xrow);
        f32x4 v1 = *reinterpret_cast<const f32x4*>(xrow + 4);
        stage(0, v0, v1);
    }
    __syncthreads();

    for (int ch = 0; ch < NCH; ++ch) {
        const int buf = ch & 1;
        // prefetch next x chunk (HBM latency overlaps this chunk's MFMAs)
        f32x4 nv0, nv1;
        if (ch + 1 < NCH) {
            nv0 = *reinterpret_cast<const f32x4*>(xrow + (ch + 1) * 64);
            nv1 = *reinterpret_cast<const f32x4*>(xrow + (ch + 1) * 64 + 4);
        }
        #pragma unroll
        for (int ks = 0; ks < 2; ++ks) {
            const int kc = (k0 >> 5) + ch * 2 + ks;
            // B fragments from global (L2-resident packed wf)
            f16x8 b[4][2];
            #pragma unroll
            for (int nt = 0; nt < 4; ++nt)
                #pragma unroll
                for (int s = 0; s < 2; ++s)
                    b[nt][s] = *reinterpret_cast<const f16x8*>(
                        &wf[(((size_t)kc * 16 + wn * 4 + nt) * 2 + s) * 512 + lane * 8]);
            // A fragments from LDS
            f16x8 a[2][2];
            #pragma unroll
            for (int mt = 0; mt < 2; ++mt)
                #pragma unroll
                for (int s = 0; s < 2; ++s)
                    a[mt][s] = *reinterpret_cast<const f16x8*>(
                        &x_lds[buf][(wm * 32 + mt * 16 + lm) * XS + s * 64 + ks * 32 + kq * 8]);
            #pragma unroll
            for (int mt = 0; mt < 2; ++mt)
                #pragma unroll
                for (int nt = 0; nt < 4; ++nt)
                    acc[mt][nt] = __builtin_amdgcn_mfma_f32_16x16x32_f16(
                        a[mt][0], b[nt][0], acc[mt][nt], 0, 0, 0);
            #pragma unroll
            for (int mt = 0; mt < 2; ++mt)
                #pragma unroll
                for (int nt = 0; nt < 4; ++nt)
                    acc[mt][nt] = __builtin_amdgcn_mfma_f32_16x16x32_f16(
                        a[mt][0], b[nt][1], acc[mt][nt], 0, 0, 0);
            #pragma unroll
            for (int mt = 0; mt < 2; ++mt)
                #pragma unroll
                for (int nt = 0; nt < 4; ++nt)
                    acc[mt][nt] = __builtin_amdgcn_mfma_f32_16x16x32_f16(
                        a[mt][1], b[nt][0], acc[mt][nt], 0, 0, 0);
        }
        if (ch + 1 < NCH) stage(buf ^ 1, nv0, nv1);
        __syncthreads();
    }

    // epilogue: raw partial logits (sigmoid applied after K-reduction)
    // C/D layout: col(expert)=lane&15, row(token)=(lane>>4)*4+reg
    float* sl = &scores[((size_t)ksl * T_TOTAL + t0) * E];
    #pragma unroll
    for (int mt = 0; mt < 2; ++mt)
        #pragma unroll
        for (int nt = 0; nt < 4; ++nt)
            #pragma unroll
            for (int r = 0; r < 4; ++r) {
                const int tok = wm * 32 + mt * 16 + kq * 4 + r;
                const int e   = wn * 64 + nt * 16 + lm;
                sl[(size_t)tok * E + e] = acc[mt][nt][r];
            }
}

// ---------------------------------------------------------------------------
// Kernel 3: reduce K-split partials, sigmoid, grouped top-k gating.
// 256 blocks x 256 threads; 32 tokens per block.
// ---------------------------------------------------------------------------
__global__ __launch_bounds__(256) void gate_kernel(
    const float* __restrict__ scores,  // [KSPLIT][T_TOTAL][E]
    const float* __restrict__ bias,    // [E]
    float* __restrict__ out)           // [T*8 idx floats][T*8 weight floats]
{
    __shared__ float sc_lds[32 * SCS];
    __shared__ float bias_lds[E];
    const int tid = threadIdx.x;
    const int t0  = blockIdx.x * 32;

    bias_lds[tid] = bias[tid];

    for (int t = 0; t < 32; ++t) {
        float s = 0.f;
        #pragma unroll
        for (int k = 0; k < KSPLIT; ++k)
            s += scores[((size_t)k * T_TOTAL + t0 + t) * E + tid];
        sc_lds[t * SCS + tid] = 1.0f / (1.0f + expf(-s));
    }
    __syncthreads();

    if (tid < 32) {
        const float* sc = &sc_lds[tid * SCS];
        float gs[N_GROUP];
        #pragma unroll
        for (int g = 0; g < N_GROUP; ++g) {
            const int base = g * GROUP_SZ;
            float m1 = -INFINITY, m2 = -INFINITY;
            for (int i = 0; i < GROUP_SZ; ++i) {
                const float v = sc[base + i] + bias_lds[base + i];
                if (v > m1) { m2 = m1; m1 = v; }
                else if (v > m2) { m2 = v; }
            }
            gs[g] = m1 + m2;
        }
        bool gsel[N_GROUP] = {false, false, false, false, false, false, false, false};
        for (int r = 0; r < TOPK_GROUP; ++r) {
            float best = -INFINITY; int bi = 0;
            for (int g = 0; g < N_GROUP; ++g)
                if (!gsel[g] && gs[g] > best) { best = gs[g]; bi = g; }
            gsel[bi] = true;
        }
        int ag[TOPK_GROUP]; int na = 0;
        for (int g = 0; g < N_GROUP; ++g) if (gsel[g]) ag[na++] = g;
        unsigned long long selmask[4] = {0ull, 0ull, 0ull, 0ull};
        int   idx[TOP_K];
        float wts[TOP_K];
        float wsum = 0.f;
        for (int r = 0; r < TOP_K; ++r) {
            float best = -INFINITY; int bi = -1;
            for (int a = 0; a < TOPK_GROUP; ++a) {
                const int base = ag[a] * GROUP_SZ;
                for (int i = 0; i < GROUP_SZ; ++i) {
                    const int e = base + i;
                    if ((selmask[e >> 6] >> (e & 63)) & 1ull) continue;
                    const float v = sc[e] + bias_lds[e];
                    if (v > best) { best = v; bi = e; }
                }
            }
            selmask[bi >> 6] |= 1ull << (bi & 63);
            idx[r] = bi;
            const float s = sc[bi];   // UNBIASED score for the weight
            wts[r] = s;
            wsum  += s;
        }
        const float scale = 2.5f / wsum;
        const int t_glob = t0 + tid;
        float* out_idx = out;
        float* out_wt  = out + (size_t)T_TOTAL * TOP_K;
        #pragma unroll
        for (int r = 0; r < TOP_K; ++r) {
            out_idx[t_glob * TOP_K + r] = (float)idx[r];
            out_wt [t_glob * TOP_K + r] = wts[r] * scale;
        }
    }
}

extern "C" void kernel_launch(void* const* d_in, const int* in_sizes, int n_in,
                              void* d_out, int out_size, void* d_ws, size_t ws_size,
                              hipStream_t stream) {
    const float* x    = (const float*)d_in[0];
    const float* w    = (const float*)d_in[1];
    const float* bias = (const float*)d_in[2];
    float* out = (float*)d_out;

    f16*   wf     = (f16*)d_ws;
    float* scores = (float*)((char*)d_ws + SCORES_OFF);   // 33.6 MB partials

    hipLaunchKernelGGL(pack_w_kernel, dim3((H / 32) * 16), dim3(64), 0, stream, w, wf);
    hipLaunchKernelGGL(gemm_kernel, dim3((T_TOTAL / MT) * KSPLIT), dim3(512), 0, stream,
                       x, wf, scores);
    hipLaunchKernelGGL(gate_kernel, dim3(T_TOTAL / 32), dim3(256), 0, stream,
                       scores, bias, out);
}